// Round 7
// baseline (292.806 us; speedup 1.0000x reference)
//
#include <hip/hip_runtime.h>

#define N_NODES 50000
#define N_EDGES 600000
#define D_IN 5
#define D_H 128
#define BN_EPS 1e-5f
#define SCAN_BLOCKS ((N_NODES + 255) / 256)   // 196
#define DEG_BLOCKS ((N_EDGES + 255) / 256)    // 2344
#define AGG32_BLOCKS ((N_NODES + 63) / 64)    // 782
#define FIX_SCALE 16777216.0f                  // 2^24
#define FIX_INV   (1.0f / 16777216.0f)

typedef __bf16 bf16x8 __attribute__((ext_vector_type(8)));
typedef float  f32x4  __attribute__((ext_vector_type(4)));

__device__ inline unsigned short f2bfb(float f) {          // fp32 -> bf16 bits, RNE
    unsigned u = __builtin_bit_cast(unsigned, f);
    unsigned r = u + 0x7fffu + ((u >> 16) & 1u);
    return (unsigned short)(r >> 16);
}
__device__ inline float bflo(unsigned u) { return __builtin_bit_cast(float, u << 16); }
__device__ inline float bfhi(unsigned u) { return __builtin_bit_cast(float, u & 0xffff0000u); }

// ---------------------------------------------------------------------------
// Stage Bt[128][128] bf16 into LDS fragment-major: frag fid=ct*4+ks at
// fid*1024 bytes; lane l's 16 B at fid*1024+l*16.
// ---------------------------------------------------------------------------
__device__ inline void stage_b(const unsigned short* __restrict__ Bt,
                               uint4* __restrict__ lds, int t)
{
#pragma unroll
    for (int i = 0; i < 8; ++i) {
        int slot = i * 256 + t;          // 0..2047
        int fid = slot >> 6;
        int l = slot & 63;
        int row = (fid >> 2) * 16 + (l & 15);
        int boff = ((l >> 4) * 16 + (fid & 3) * 64) >> 1;   // in shorts
        lds[slot] = *(const uint4*)(Bt + row * D_H + boff);
    }
}

// ---------------------------------------------------------------------------
// Fused prep: [0,192) weight transpose+bf16; [192,388) BN0 stats;
// [388, 388+DEG_BLOCKS) per-edge u64 deg/count atomic + rank capture.
// ---------------------------------------------------------------------------
__global__ __launch_bounds__(256) void k_prep(const float* __restrict__ W2,
                                              const float* __restrict__ Wmu,
                                              const float* __restrict__ Wls,
                                              unsigned short* __restrict__ T2,
                                              unsigned short* __restrict__ Tmu,
                                              unsigned short* __restrict__ Tls,
                                              const float* __restrict__ h,
                                              float* __restrict__ stats0,
                                              const int* __restrict__ dst,
                                              const float* __restrict__ w,
                                              unsigned long long* __restrict__ degcnt,
                                              int* __restrict__ rank)
{
    __shared__ float ss[D_IN], sq[D_IN];
    int b = blockIdx.x;
    int t = threadIdx.x;
    if (b < 192) {
        int mat = b >> 6;
        int idx = (b & 63) * 256 + t;   // < 16384
        const float* W = (mat == 0) ? W2 : (mat == 1) ? Wmu : Wls;
        unsigned short* T = (mat == 0) ? T2 : (mat == 1) ? Tmu : Tls;
        int k = idx >> 7, n = idx & 127;
        T[n * D_H + k] = f2bfb(W[idx]);
    } else if (b < 192 + SCAN_BLOCKS) {
        if (t < D_IN) { ss[t] = 0.f; sq[t] = 0.f; }
        __syncthreads();
        int node = (b - 192) * 256 + t;
        float v[D_IN];
#pragma unroll
        for (int f = 0; f < D_IN; ++f)
            v[f] = (node < N_NODES) ? h[node * D_IN + f] : 0.f;
        int lane = t & 63;
#pragma unroll
        for (int f = 0; f < D_IN; ++f) {
            float s = v[f], q = v[f] * v[f];
            for (int off = 32; off > 0; off >>= 1) {
                s += __shfl_down(s, off);
                q += __shfl_down(q, off);
            }
            if (lane == 0) { atomicAdd(&ss[f], s); atomicAdd(&sq[f], q); }
        }
        __syncthreads();
        if (t < D_IN) {
            atomicAdd(&stats0[t], ss[t]);
            atomicAdd(&stats0[D_IN + t], sq[t]);
        }
    } else {
        int e = (b - 192 - SCAN_BLOCKS) * 256 + t;
        if (e < N_EDGES) {
            int d = dst[e];
            unsigned long long fx = (unsigned long long)(w[e] * FIX_SCALE + 0.5f);
            unsigned long long old = atomicAdd(degcnt + d, (1ull << 40) | fx);
            rank[e] = (int)(old >> 40);
        }
    }
}

// ---------------------------------------------------------------------------
__global__ __launch_bounds__(256) void k_scan1(const unsigned long long* __restrict__ degcnt,
                                               float* __restrict__ dis,
                                               int* __restrict__ blocksums)
{
    __shared__ int sm[256];
    int t = threadIdx.x;
    int i = blockIdx.x * 256 + t;
    int c = 0;
    if (i < N_NODES) {
        unsigned long long v = degcnt[i];
        c = (int)(v >> 40);
        float deg = (float)(v & ((1ull << 40) - 1)) * FIX_INV;
        dis[i] = rsqrtf(deg + 1.0f);
    }
    sm[t] = c;
    __syncthreads();
    for (int off = 128; off > 0; off >>= 1) {
        if (t < off) sm[t] += sm[t + off];
        __syncthreads();
    }
    if (t == 0) blocksums[blockIdx.x] = sm[0];
}

// ---------------------------------------------------------------------------
// scan2 folded in: each block sums the preceding block totals itself
// (<=196 ints), then does its intra-block exclusive scan. rowptr[N] = E.
// ---------------------------------------------------------------------------
__global__ __launch_bounds__(256) void k_scan3(const unsigned long long* __restrict__ degcnt,
                                               int* __restrict__ rowptr,
                                               const int* __restrict__ blocksums)
{
    __shared__ int sm[256];
    __shared__ int soff;
    int t = threadIdx.x;
    int bid = blockIdx.x;
    int pre = (t < bid) ? blocksums[t] : 0;    // bid <= 195 < 256
    sm[t] = pre;
    __syncthreads();
    for (int off = 128; off > 0; off >>= 1) {
        if (t < off) sm[t] += sm[t + off];
        __syncthreads();
    }
    if (t == 0) soff = sm[0];
    __syncthreads();
    int i = bid * 256 + t;
    int c = (i < N_NODES) ? (int)(degcnt[i] >> 40) : 0;
    sm[t] = c;
    __syncthreads();
    for (int off = 1; off < 256; off <<= 1) {
        int v = (t >= off) ? sm[t - off] : 0;
        __syncthreads();
        sm[t] += v;
        __syncthreads();
    }
    if (i < N_NODES)
        rowptr[i] = soff + sm[t] - c;
    if (bid == 0 && t == 0)
        rowptr[N_NODES] = N_EDGES;
}

// ---------------------------------------------------------------------------
// Fill CSR, atomic-free: pos = rowptr[dst] + rank. csr = {src, dis[src]*w}
// (dis[dst] factored out into the aggregation epilogue).
// ---------------------------------------------------------------------------
__global__ __launch_bounds__(256) void k_fill(const int* __restrict__ src,
                                              const int* __restrict__ dst,
                                              const float* __restrict__ w,
                                              const float* __restrict__ dis,
                                              const int* __restrict__ rowptr,
                                              const int* __restrict__ rank,
                                              int2* __restrict__ csr)
{
    int e = blockIdx.x * blockDim.x + threadIdx.x;
    if (e < N_EDGES) {
        int s = src[e], d = dst[e];
        float pn = dis[s] * w[e];
        int pos = rowptr[d] + rank[e];
        int2 pk;
        pk.x = s;
        pk.y = __builtin_bit_cast(int, pn);
        csr[pos] = pk;
    }
}

// ---------------------------------------------------------------------------
// Aggregate BN0(h) at width 5 (node-parallel, R1-proven; 196 blocks all
// co-resident, h is 1 MB = L2-resident -> no cache-capacity issue here).
// Epilogue: Sa[5] + Saa[15] moments for closed-form BN1.
// ---------------------------------------------------------------------------
__global__ __launch_bounds__(256) void k_agg0(const float* __restrict__ h,
                                              const float* __restrict__ stats,
                                              const float* __restrict__ g0,
                                              const float* __restrict__ be0,
                                              const int* __restrict__ rowptr,
                                              const int2* __restrict__ csr,
                                              const float* __restrict__ dis,
                                              float* __restrict__ agg,
                                              float* __restrict__ statsA)
{
    __shared__ float sA[20];
    int t = threadIdx.x;
    if (t < 20) sA[t] = 0.f;
    __syncthreads();
    int n = blockIdx.x * 256 + t;
    float av[D_IN] = {0.f, 0.f, 0.f, 0.f, 0.f};
    if (n < N_NODES) {
        float sc[D_IN], sh[D_IN];
#pragma unroll
        for (int f = 0; f < D_IN; ++f) {
            float m = stats[f] * (1.0f / N_NODES);
            float var = stats[D_IN + f] * (1.0f / N_NODES) - m * m;
            sc[f] = rsqrtf(var + BN_EPS) * g0[f];
            sh[f] = be0[f] - m * sc[f];
        }
        float dn = dis[n];
        float acc[D_IN];
#pragma unroll
        for (int f = 0; f < D_IN; ++f)
            acc[f] = dn * (h[n * D_IN + f] * sc[f] + sh[f]);
        int e0 = rowptr[n], e1 = rowptr[n + 1];
        for (int e = e0; e < e1; ++e) {
            int2 pk = csr[e];
            int s = pk.x;
            float pn = __builtin_bit_cast(float, pk.y);
#pragma unroll
            for (int f = 0; f < D_IN; ++f)
                acc[f] += pn * (h[s * D_IN + f] * sc[f] + sh[f]);
        }
#pragma unroll
        for (int f = 0; f < D_IN; ++f) {
            float o = dn * acc[f];
            agg[n * D_IN + f] = o;
            av[f] = o;
        }
    }
    // 20-value reduction: Sa[0..4], then Saa upper triangle (k<=l)
    float red[20];
#pragma unroll
    for (int f = 0; f < D_IN; ++f) red[f] = av[f];
    {
        int idx = D_IN;
#pragma unroll
        for (int k = 0; k < D_IN; ++k)
#pragma unroll
            for (int l = k; l < D_IN; ++l)
                red[idx++] = av[k] * av[l];
    }
#pragma unroll
    for (int off = 32; off > 0; off >>= 1) {
#pragma unroll
        for (int i = 0; i < 20; ++i)
            red[i] += __shfl_down(red[i], off);
    }
    if ((t & 63) == 0) {
#pragma unroll
        for (int i = 0; i < 20; ++i)
            atomicAdd(&sA[i], red[i]);
    }
    __syncthreads();
    if (t < 20) atomicAdd(statsA + t, sA[t]);
}

// ---------------------------------------------------------------------------
// Layer-1 skinny GEMM (K=5) with fused CLOSED-FORM BN1 + ReLU applied in fp32
// before the bf16 round. MUST be launched with exactly 512 blocks x 256 thr.
// ---------------------------------------------------------------------------
__global__ __launch_bounds__(256) void k_l1(const float* __restrict__ agg,
                                            const float* __restrict__ W1,
                                            const float* __restrict__ b1,
                                            const float* __restrict__ g1,
                                            const float* __restrict__ be1,
                                            const float* __restrict__ statsA,
                                            unsigned short* __restrict__ x)
{
    int t = threadIdx.x;
    int idx0 = blockIdx.x * 256 + t;
    int f0 = (idx0 & 63) * 2;      // feature pair, constant per thread
    float wa[D_IN], wb[D_IN];
#pragma unroll
    for (int k = 0; k < D_IN; ++k) {
        wa[k] = W1[k * D_H + f0];
        wb[k] = W1[k * D_H + f0 + 1];
    }
    float ba = b1[f0], bb = b1[f0 + 1];

    // closed-form BN1 affine for this feature pair
    const float inv = 1.0f / N_NODES;
    float S1[D_IN];
#pragma unroll
    for (int k = 0; k < D_IN; ++k) S1[k] = statsA[k];
    float M[D_IN][D_IN];
    {
        int idx = D_IN;
#pragma unroll
        for (int k = 0; k < D_IN; ++k)
#pragma unroll
            for (int l = k; l < D_IN; ++l) {
                float v = statsA[idx++];
                M[k][l] = v;
                M[l][k] = v;
            }
    }
    float t1a = 0.f, t1b = 0.f, qa = 0.f, qb = 0.f;
#pragma unroll
    for (int k = 0; k < D_IN; ++k) { t1a += wa[k] * S1[k]; t1b += wb[k] * S1[k]; }
#pragma unroll
    for (int k = 0; k < D_IN; ++k) {
        float ra = 0.f, rb = 0.f;
#pragma unroll
        for (int l = 0; l < D_IN; ++l) { ra += M[k][l] * wa[l]; rb += M[k][l] * wb[l]; }
        qa += wa[k] * ra;
        qb += wb[k] * rb;
    }
    float ma = t1a * inv, mb = t1b * inv;           // mean of w.a (bias excluded)
    float mua = ma + ba, mub = mb + bb;
    float vara = fmaxf(qa * inv - ma * ma, 0.f);
    float varb = fmaxf(qb * inv - mb * mb, 0.f);
    float sca = rsqrtf(vara + BN_EPS) * g1[f0];
    float scb = rsqrtf(varb + BN_EPS) * g1[f0 + 1];
    float sha = be1[f0] - mua * sca;
    float shb = be1[f0 + 1] - mub * scb;

    const int stride = 512 * 256;
    for (int idx = idx0; idx < N_NODES * 64; idx += stride) {
        int n = idx >> 6;
        const float* a = agg + n * D_IN;
        float v0 = ba, v1 = bb;
#pragma unroll
        for (int k = 0; k < D_IN; ++k) { v0 += wa[k] * a[k]; v1 += wb[k] * a[k]; }
        v0 = fmaxf(v0 * sca + sha, 0.f);
        v1 = fmaxf(v1 * scb + shb, 0.f);
        ((unsigned*)x)[idx] = (unsigned)f2bfb(v0) | ((unsigned)f2bfb(v1) << 16);
    }
}

// ---------------------------------------------------------------------------
// Feature-sliced aggregation pass: gathers ONLY features [fq*32, fq*32+32).
// Per pass the gathered slice is 50000*64B = 3.2 MB < 4 MB L2/XCD, so after
// compulsory fill every edge-gather is an L2 hit (one 64B line per edge per
// 4-lane group). 4 independent passes cover all 128 features; per-feature
// edge accumulation order identical to the monolithic kernel.
// ---------------------------------------------------------------------------
__global__ __launch_bounds__(256) void k_agg32(const unsigned short* __restrict__ x,
                                               const int* __restrict__ rowptr,
                                               const int2* __restrict__ csr,
                                               const float* __restrict__ dis,
                                               unsigned short* __restrict__ outb,
                                               int fq)
{
    int t = threadIdx.x;
    int n = blockIdx.x * 64 + (t >> 2);
    if (n >= N_NODES) return;
    int f0 = fq * 32 + (t & 3) * 8;
    float dn = dis[n];
    uint4 hv = *(const uint4*)(x + (size_t)n * D_H + f0);
    float a0 = dn * bflo(hv.x), a1 = dn * bfhi(hv.x);
    float a2 = dn * bflo(hv.y), a3 = dn * bfhi(hv.y);
    float a4 = dn * bflo(hv.z), a5 = dn * bfhi(hv.z);
    float a6 = dn * bflo(hv.w), a7 = dn * bfhi(hv.w);
    int e = rowptr[n], e1 = rowptr[n + 1];
    for (; e + 8 <= e1; e += 8) {
        int2 p0 = csr[e + 0], p1 = csr[e + 1], p2 = csr[e + 2], p3 = csr[e + 3];
        int2 p4 = csr[e + 4], p5 = csr[e + 5], p6 = csr[e + 6], p7 = csr[e + 7];
        uint4 v0 = *(const uint4*)(x + (size_t)p0.x * D_H + f0);
        uint4 v1 = *(const uint4*)(x + (size_t)p1.x * D_H + f0);
        uint4 v2 = *(const uint4*)(x + (size_t)p2.x * D_H + f0);
        uint4 v3 = *(const uint4*)(x + (size_t)p3.x * D_H + f0);
        uint4 v4 = *(const uint4*)(x + (size_t)p4.x * D_H + f0);
        uint4 v5 = *(const uint4*)(x + (size_t)p5.x * D_H + f0);
        uint4 v6 = *(const uint4*)(x + (size_t)p6.x * D_H + f0);
        uint4 v7 = *(const uint4*)(x + (size_t)p7.x * D_H + f0);
        float w0 = __builtin_bit_cast(float, p0.y), w1 = __builtin_bit_cast(float, p1.y);
        float w2 = __builtin_bit_cast(float, p2.y), w3 = __builtin_bit_cast(float, p3.y);
        float w4 = __builtin_bit_cast(float, p4.y), w5 = __builtin_bit_cast(float, p5.y);
        float w6 = __builtin_bit_cast(float, p6.y), w7 = __builtin_bit_cast(float, p7.y);
        a0 += w0 * bflo(v0.x) + w1 * bflo(v1.x) + w2 * bflo(v2.x) + w3 * bflo(v3.x)
            + w4 * bflo(v4.x) + w5 * bflo(v5.x) + w6 * bflo(v6.x) + w7 * bflo(v7.x);
        a1 += w0 * bfhi(v0.x) + w1 * bfhi(v1.x) + w2 * bfhi(v2.x) + w3 * bfhi(v3.x)
            + w4 * bfhi(v4.x) + w5 * bfhi(v5.x) + w6 * bfhi(v6.x) + w7 * bfhi(v7.x);
        a2 += w0 * bflo(v0.y) + w1 * bflo(v1.y) + w2 * bflo(v2.y) + w3 * bflo(v3.y)
            + w4 * bflo(v4.y) + w5 * bflo(v5.y) + w6 * bflo(v6.y) + w7 * bflo(v7.y);
        a3 += w0 * bfhi(v0.y) + w1 * bfhi(v1.y) + w2 * bfhi(v2.y) + w3 * bfhi(v3.y)
            + w4 * bfhi(v4.y) + w5 * bfhi(v5.y) + w6 * bfhi(v6.y) + w7 * bfhi(v7.y);
        a4 += w0 * bflo(v0.z) + w1 * bflo(v1.z) + w2 * bflo(v2.z) + w3 * bflo(v3.z)
            + w4 * bflo(v4.z) + w5 * bflo(v5.z) + w6 * bflo(v6.z) + w7 * bflo(v7.z);
        a5 += w0 * bfhi(v0.z) + w1 * bfhi(v1.z) + w2 * bfhi(v2.z) + w3 * bfhi(v3.z)
            + w4 * bfhi(v4.z) + w5 * bfhi(v5.z) + w6 * bfhi(v6.z) + w7 * bfhi(v7.z);
        a6 += w0 * bflo(v0.w) + w1 * bflo(v1.w) + w2 * bflo(v2.w) + w3 * bflo(v3.w)
            + w4 * bflo(v4.w) + w5 * bflo(v5.w) + w6 * bflo(v6.w) + w7 * bflo(v7.w);
        a7 += w0 * bfhi(v0.w) + w1 * bfhi(v1.w) + w2 * bfhi(v2.w) + w3 * bfhi(v3.w)
            + w4 * bfhi(v4.w) + w5 * bfhi(v5.w) + w6 * bfhi(v6.w) + w7 * bfhi(v7.w);
    }
    for (; e < e1; ++e) {
        int2 pk = csr[e];
        float pn = __builtin_bit_cast(float, pk.y);
        uint4 v = *(const uint4*)(x + (size_t)pk.x * D_H + f0);
        a0 += pn * bflo(v.x); a1 += pn * bfhi(v.x);
        a2 += pn * bflo(v.y); a3 += pn * bfhi(v.y);
        a4 += pn * bflo(v.z); a5 += pn * bfhi(v.z);
        a6 += pn * bflo(v.w); a7 += pn * bfhi(v.w);
    }
    uint4 o;
    o.x = (unsigned)f2bfb(dn * a0) | ((unsigned)f2bfb(dn * a1) << 16);
    o.y = (unsigned)f2bfb(dn * a2) | ((unsigned)f2bfb(dn * a3) << 16);
    o.z = (unsigned)f2bfb(dn * a4) | ((unsigned)f2bfb(dn * a5) << 16);
    o.w = (unsigned)f2bfb(dn * a6) | ((unsigned)f2bfb(dn * a7) << 16);
    *(uint4*)(outb + (size_t)n * D_H + f0) = o;
}

// ---------------------------------------------------------------------------
// MFMA GEMM, LDS-staged B: C_bf16 = A_bf16 @ W + bias (pre-BN), fused stats.
// ---------------------------------------------------------------------------
__global__ __launch_bounds__(256) void k_gemm_mf(const unsigned short* __restrict__ A,
                                                 const unsigned short* __restrict__ Bt,
                                                 const float* __restrict__ bias,
                                                 unsigned short* __restrict__ C,
                                                 float* __restrict__ stats)
{
    __shared__ uint4 ldsB[2048];          // 32 KB fragment-major B
    __shared__ float sm_s[D_H], sm_q[D_H];
    int t = threadIdx.x;
    if (t < D_H) { sm_s[t] = 0.f; sm_q[t] = 0.f; }
    stage_b(Bt, ldsB, t);
    int wave = t >> 6, lane = t & 63;
    int m = lane & 15, quad = lane >> 4;
    int r0 = blockIdx.x * 64 + wave * 16;
    int arow = r0 + m < N_NODES ? r0 + m : N_NODES - 1;
    const bf16x8* ap = (const bf16x8*)(A + (size_t)arow * D_H + quad * 8);
    bf16x8 af[4];
#pragma unroll
    for (int ks = 0; ks < 4; ++ks) af[ks] = ap[ks * 4];
    __syncthreads();
    const bf16x8* bf = (const bf16x8*)ldsB;       // [fid*64 + lane]
    f32x4 acc[8];
#pragma unroll
    for (int ct = 0; ct < 8; ++ct) acc[ct] = (f32x4)(0.f);
#pragma unroll
    for (int ks = 0; ks < 4; ++ks) {
#pragma unroll
        for (int ct = 0; ct < 8; ++ct) {
            acc[ct] = __builtin_amdgcn_mfma_f32_16x16x32_bf16(
                af[ks], bf[(ct * 4 + ks) * 64 + lane], acc[ct], 0, 0, 0);
        }
    }
#pragma unroll
    for (int ct = 0; ct < 8; ++ct) {
        int col = ct * 16 + m;
        float bv = bias[col];
        float s = 0.f, q = 0.f;
#pragma unroll
        for (int r = 0; r < 4; ++r) {
            int rr = r0 + quad * 4 + r;
            if (rr < N_NODES) {
                float v = acc[ct][r] + bv;
                C[(size_t)rr * D_H + col] = f2bfb(v);
                s += v; q += v * v;
            }
        }
        atomicAdd(&sm_s[col], s);
        atomicAdd(&sm_q[col], q);
    }
    __syncthreads();
    if (t < D_H) {
        atomicAdd(stats + t, sm_s[t]);
        atomicAdd(stats + D_H + t, sm_q[t]);
    }
}

// ---------------------------------------------------------------------------
// MFMA dual GEMM with fused BN2+ReLU on the A fragments.
// mu -> out[0:N*128), log_std -> out[N*128:). fp32 out.
// ---------------------------------------------------------------------------
__global__ __launch_bounds__(256) void k_gemm_out_mf(const unsigned short* __restrict__ A,
                                                     const float* __restrict__ stats,
                                                     const float* __restrict__ g,
                                                     const float* __restrict__ be,
                                                     const unsigned short* __restrict__ Btmu,
                                                     const float* __restrict__ bmu,
                                                     const unsigned short* __restrict__ Btls,
                                                     const float* __restrict__ bls,
                                                     float* __restrict__ out)
{
    __shared__ uint4 ldsB[2048];          // 32 KB fragment-major B
    int t = threadIdx.x;
    int wave = t >> 6, lane = t & 63;
    int m = lane & 15, quad = lane >> 4;
    int r0 = blockIdx.x * 64 + wave * 16;
    int arow = r0 + m < N_NODES ? r0 + m : N_NODES - 1;
    const unsigned short* arowp = A + (size_t)arow * D_H + quad * 8;
    const float inv = 1.0f / N_NODES;
    bf16x8 af[4];
#pragma unroll
    for (int ks = 0; ks < 4; ++ks) {
        uint4 av = *(const uint4*)(arowp + ks * 32);
        float vals[8] = { bflo(av.x), bfhi(av.x), bflo(av.y), bfhi(av.y),
                          bflo(av.z), bfhi(av.z), bflo(av.w), bfhi(av.w) };
        int fb = quad * 8 + ks * 32;
        unsigned short o[8];
#pragma unroll
        for (int j = 0; j < 8; ++j) {
            int f = fb + j;
            float mm = stats[f] * inv;
            float var = stats[D_H + f] * inv - mm * mm;
            float scv = rsqrtf(var + BN_EPS) * g[f];
            float shv = be[f] - mm * scv;
            o[j] = f2bfb(fmaxf(vals[j] * scv + shv, 0.f));
        }
        uint4 pk;
        pk.x = (unsigned)o[0] | ((unsigned)o[1] << 16);
        pk.y = (unsigned)o[2] | ((unsigned)o[3] << 16);
        pk.z = (unsigned)o[4] | ((unsigned)o[5] << 16);
        pk.w = (unsigned)o[6] | ((unsigned)o[7] << 16);
        af[ks] = __builtin_bit_cast(bf16x8, pk);
    }
    const bf16x8* bf = (const bf16x8*)ldsB;
#pragma unroll
    for (int half = 0; half < 2; ++half) {
        if (half) __syncthreads();        // protect restage vs prior reads
        stage_b(half ? Btls : Btmu, ldsB, t);
        __syncthreads();
        const float* bias = half ? bls : bmu;
        float* C = out + (half ? (size_t)N_NODES * D_H : 0);
        f32x4 acc[8];
#pragma unroll
        for (int ct = 0; ct < 8; ++ct) acc[ct] = (f32x4)(0.f);
#pragma unroll
        for (int ks = 0; ks < 4; ++ks) {
#pragma unroll
            for (int ct = 0; ct < 8; ++ct) {
                acc[ct] = __builtin_amdgcn_mfma_f32_16x16x32_bf16(
                    af[ks], bf[(ct * 4 + ks) * 64 + lane], acc[ct], 0, 0, 0);
            }
        }
#pragma unroll
        for (int ct = 0; ct < 8; ++ct) {
            int col = ct * 16 + m;
            float bv = bias[col];
#pragma unroll
            for (int r = 0; r < 4; ++r) {
                int rr = r0 + quad * 4 + r;
                if (rr < N_NODES)
                    C[(size_t)rr * D_H + col] = acc[ct][r] + bv;
            }
        }
    }
}

// ---------------------------------------------------------------------------
extern "C" void kernel_launch(void* const* d_in, const int* in_sizes, int n_in,
                              void* d_out, int out_size, void* d_ws, size_t ws_size,
                              hipStream_t stream)
{
    const float* h   = (const float*)d_in[0];
    const int*   eidx = (const int*)d_in[1];
    const float* ew  = (const float*)d_in[2];
    const float* g0  = (const float*)d_in[3];
    const float* be0 = (const float*)d_in[4];
    const float* W1  = (const float*)d_in[5];
    const float* b1  = (const float*)d_in[6];
    const float* g1  = (const float*)d_in[7];
    const float* be1 = (const float*)d_in[8];
    const float* W2  = (const float*)d_in[9];
    const float* b2  = (const float*)d_in[10];
    const float* g2  = (const float*)d_in[11];
    const float* be2 = (const float*)d_in[12];
    const float* Wmu = (const float*)d_in[13];
    const float* bmu = (const float*)d_in[14];
    const float* Wls = (const float*)d_in[15];
    const float* bls = (const float*)d_in[16];
    const int* srcv = eidx;
    const int* dstv = eidx + N_EDGES;
    float* out = (float*)d_out;

    char* ws = (char*)d_ws;
    size_t off = 0;
    auto alloc = [&](size_t bytes) -> char* {
        char* p = ws + off;
        off += (bytes + 255) & ~(size_t)255;
        return p;
    };
    float* stats0  = (float*)alloc(16 * 4);
    float* statsA  = (float*)alloc(32 * 4);     // 20 used: Sa[5] + Saa[15]
    float* stats2  = (float*)alloc(256 * 4);
    unsigned long long* degcnt = (unsigned long long*)alloc(N_NODES * 8);
    size_t zero_bytes = off;                 // everything above must start at 0
    int*   rowptr  = (int*)  alloc((N_NODES + 1) * 4);
    float* dis     = (float*)alloc(N_NODES * 4);
    int*   rank    = (int*)  alloc((size_t)N_EDGES * 4);
    int*   blocksums = (int*)alloc(256 * 4);
    int2*  csr     = (int2*) alloc((size_t)N_EDGES * 8);
    float* agg0    = (float*)alloc(N_NODES * D_IN * 4);
    unsigned short* x1h  = (unsigned short*)alloc((size_t)N_NODES * D_H * 2);  // bf16 post-BN1+ReLU
    unsigned short* aggh = (unsigned short*)alloc((size_t)N_NODES * D_H * 2);  // bf16 agg
    unsigned short* c2h  = (unsigned short*)alloc((size_t)N_NODES * D_H * 2);  // bf16 pre-BN2
    unsigned short* Wt2   = (unsigned short*)alloc(D_H * D_H * 2);
    unsigned short* Wtmu  = (unsigned short*)alloc(D_H * D_H * 2);
    unsigned short* Wtls  = (unsigned short*)alloc(D_H * D_H * 2);
    (void)ws_size; (void)in_sizes; (void)n_in; (void)out_size;

    hipMemsetAsync(d_ws, 0, zero_bytes, stream);

    k_prep<<<192 + SCAN_BLOCKS + DEG_BLOCKS, 256, 0, stream>>>(
        W2, Wmu, Wls, Wt2, Wtmu, Wtls, h, stats0, dstv, ew, degcnt, rank);
    k_scan1<<<SCAN_BLOCKS, 256, 0, stream>>>(degcnt, dis, blocksums);
    k_scan3<<<SCAN_BLOCKS, 256, 0, stream>>>(degcnt, rowptr, blocksums);
    k_fill<<<DEG_BLOCKS, 256, 0, stream>>>(srcv, dstv, ew, dis, rowptr, rank, csr);
    k_agg0<<<SCAN_BLOCKS, 256, 0, stream>>>(h, stats0, g0, be0, rowptr, csr, dis,
                                            agg0, statsA);
    k_l1<<<512, 256, 0, stream>>>(agg0, W1, b1, g1, be1, statsA, x1h);
    k_agg32<<<AGG32_BLOCKS, 256, 0, stream>>>(x1h, rowptr, csr, dis, aggh, 0);
    k_agg32<<<AGG32_BLOCKS, 256, 0, stream>>>(x1h, rowptr, csr, dis, aggh, 1);
    k_agg32<<<AGG32_BLOCKS, 256, 0, stream>>>(x1h, rowptr, csr, dis, aggh, 2);
    k_agg32<<<AGG32_BLOCKS, 256, 0, stream>>>(x1h, rowptr, csr, dis, aggh, 3);
    k_gemm_mf<<<(N_NODES + 63) / 64, 256, 0, stream>>>(aggh, Wt2, b2, c2h, stats2);
    k_gemm_out_mf<<<(N_NODES + 63) / 64, 256, 0, stream>>>(c2h, stats2, g2, be2,
                                                           Wtmu, bmu, Wtls, bls, out);
}

// Round 8
// 262.437 us; speedup vs baseline: 1.1157x; 1.1157x over previous
//
#include <hip/hip_runtime.h>

#define N_NODES 50000
#define N_EDGES 600000
#define D_IN 5
#define D_H 128
#define BN_EPS 1e-5f
#define SCAN_BLOCKS ((N_NODES + 255) / 256)   // 196
#define DEG_BLOCKS ((N_EDGES + 255) / 256)    // 2344
#define FIX_SCALE 16777216.0f                  // 2^24
#define FIX_INV   (1.0f / 16777216.0f)

typedef __bf16 bf16x8 __attribute__((ext_vector_type(8)));
typedef float  f32x4  __attribute__((ext_vector_type(4)));

__device__ inline unsigned short f2bfb(float f) {          // fp32 -> bf16 bits, RNE
    unsigned u = __builtin_bit_cast(unsigned, f);
    unsigned r = u + 0x7fffu + ((u >> 16) & 1u);
    return (unsigned short)(r >> 16);
}
__device__ inline float bflo(unsigned u) { return __builtin_bit_cast(float, u << 16); }
__device__ inline float bfhi(unsigned u) { return __builtin_bit_cast(float, u & 0xffff0000u); }

// ---------------------------------------------------------------------------
// Stage Bt[128][128] bf16 into LDS fragment-major: frag fid=ct*4+ks at
// fid*1024 bytes; lane l's 16 B at fid*1024+l*16.
// ---------------------------------------------------------------------------
__device__ inline void stage_b(const unsigned short* __restrict__ Bt,
                               uint4* __restrict__ lds, int t)
{
#pragma unroll
    for (int i = 0; i < 8; ++i) {
        int slot = i * 256 + t;          // 0..2047
        int fid = slot >> 6;
        int l = slot & 63;
        int row = (fid >> 2) * 16 + (l & 15);
        int boff = ((l >> 4) * 16 + (fid & 3) * 64) >> 1;   // in shorts
        lds[slot] = *(const uint4*)(Bt + row * D_H + boff);
    }
}

// ---------------------------------------------------------------------------
// Fused prep: [0,192) weight transpose+bf16; [192,388) BN0 stats;
// [388, 388+DEG_BLOCKS) per-edge u64 deg/count atomic + rank capture.
// ---------------------------------------------------------------------------
__global__ __launch_bounds__(256) void k_prep(const float* __restrict__ W2,
                                              const float* __restrict__ Wmu,
                                              const float* __restrict__ Wls,
                                              unsigned short* __restrict__ T2,
                                              unsigned short* __restrict__ Tmu,
                                              unsigned short* __restrict__ Tls,
                                              const float* __restrict__ h,
                                              float* __restrict__ stats0,
                                              const int* __restrict__ dst,
                                              const float* __restrict__ w,
                                              unsigned long long* __restrict__ degcnt,
                                              int* __restrict__ rank)
{
    __shared__ float ss[D_IN], sq[D_IN];
    int b = blockIdx.x;
    int t = threadIdx.x;
    if (b < 192) {
        int mat = b >> 6;
        int idx = (b & 63) * 256 + t;   // < 16384
        const float* W = (mat == 0) ? W2 : (mat == 1) ? Wmu : Wls;
        unsigned short* T = (mat == 0) ? T2 : (mat == 1) ? Tmu : Tls;
        int k = idx >> 7, n = idx & 127;
        T[n * D_H + k] = f2bfb(W[idx]);
    } else if (b < 192 + SCAN_BLOCKS) {
        if (t < D_IN) { ss[t] = 0.f; sq[t] = 0.f; }
        __syncthreads();
        int node = (b - 192) * 256 + t;
        float v[D_IN];
#pragma unroll
        for (int f = 0; f < D_IN; ++f)
            v[f] = (node < N_NODES) ? h[node * D_IN + f] : 0.f;
        int lane = t & 63;
#pragma unroll
        for (int f = 0; f < D_IN; ++f) {
            float s = v[f], q = v[f] * v[f];
            for (int off = 32; off > 0; off >>= 1) {
                s += __shfl_down(s, off);
                q += __shfl_down(q, off);
            }
            if (lane == 0) { atomicAdd(&ss[f], s); atomicAdd(&sq[f], q); }
        }
        __syncthreads();
        if (t < D_IN) {
            atomicAdd(&stats0[t], ss[t]);
            atomicAdd(&stats0[D_IN + t], sq[t]);
        }
    } else {
        int e = (b - 192 - SCAN_BLOCKS) * 256 + t;
        if (e < N_EDGES) {
            int d = dst[e];
            unsigned long long fx = (unsigned long long)(w[e] * FIX_SCALE + 0.5f);
            unsigned long long old = atomicAdd(degcnt + d, (1ull << 40) | fx);
            rank[e] = (int)(old >> 40);
        }
    }
}

// ---------------------------------------------------------------------------
__global__ __launch_bounds__(256) void k_scan1(const unsigned long long* __restrict__ degcnt,
                                               float* __restrict__ dis,
                                               int* __restrict__ blocksums)
{
    __shared__ int sm[256];
    int t = threadIdx.x;
    int i = blockIdx.x * 256 + t;
    int c = 0;
    if (i < N_NODES) {
        unsigned long long v = degcnt[i];
        c = (int)(v >> 40);
        float deg = (float)(v & ((1ull << 40) - 1)) * FIX_INV;
        dis[i] = rsqrtf(deg + 1.0f);
    }
    sm[t] = c;
    __syncthreads();
    for (int off = 128; off > 0; off >>= 1) {
        if (t < off) sm[t] += sm[t + off];
        __syncthreads();
    }
    if (t == 0) blocksums[blockIdx.x] = sm[0];
}

// ---------------------------------------------------------------------------
// scan2 folded in: each block sums the preceding block totals itself
// (<=196 ints), then does its intra-block exclusive scan. rowptr[N] = E.
// ---------------------------------------------------------------------------
__global__ __launch_bounds__(256) void k_scan3(const unsigned long long* __restrict__ degcnt,
                                               int* __restrict__ rowptr,
                                               const int* __restrict__ blocksums)
{
    __shared__ int sm[256];
    __shared__ int soff;
    int t = threadIdx.x;
    int bid = blockIdx.x;
    int pre = (t < bid) ? blocksums[t] : 0;    // bid <= 195 < 256
    sm[t] = pre;
    __syncthreads();
    for (int off = 128; off > 0; off >>= 1) {
        if (t < off) sm[t] += sm[t + off];
        __syncthreads();
    }
    if (t == 0) soff = sm[0];
    __syncthreads();
    int i = bid * 256 + t;
    int c = (i < N_NODES) ? (int)(degcnt[i] >> 40) : 0;
    sm[t] = c;
    __syncthreads();
    for (int off = 1; off < 256; off <<= 1) {
        int v = (t >= off) ? sm[t - off] : 0;
        __syncthreads();
        sm[t] += v;
        __syncthreads();
    }
    if (i < N_NODES)
        rowptr[i] = soff + sm[t] - c;
    if (bid == 0 && t == 0)
        rowptr[N_NODES] = N_EDGES;
}

// ---------------------------------------------------------------------------
// Fill CSR, atomic-free: pos = rowptr[dst] + rank. csr = {src, dis[src]*w}
// (dis[dst] factored out into the aggregation epilogue).
// ---------------------------------------------------------------------------
__global__ __launch_bounds__(256) void k_fill(const int* __restrict__ src,
                                              const int* __restrict__ dst,
                                              const float* __restrict__ w,
                                              const float* __restrict__ dis,
                                              const int* __restrict__ rowptr,
                                              const int* __restrict__ rank,
                                              int2* __restrict__ csr)
{
    int e = blockIdx.x * blockDim.x + threadIdx.x;
    if (e < N_EDGES) {
        int s = src[e], d = dst[e];
        float pn = dis[s] * w[e];
        int pos = rowptr[d] + rank[e];
        int2 pk;
        pk.x = s;
        pk.y = __builtin_bit_cast(int, pn);
        csr[pos] = pk;
    }
}

// ---------------------------------------------------------------------------
// Aggregate BN0(h) at width 5. out[n] = dis[n]*(dis[n]*bn(h[n]) + sum pn*bn(h[s]))
// Epilogue: first+second moments of the output rows (Sa[5], Saa[15]) for the
// closed-form BN1 statistics (x = agg @ W1 + b1 is affine in agg).
// ---------------------------------------------------------------------------
__global__ __launch_bounds__(256) void k_agg0(const float* __restrict__ h,
                                              const float* __restrict__ stats,
                                              const float* __restrict__ g0,
                                              const float* __restrict__ be0,
                                              const int* __restrict__ rowptr,
                                              const int2* __restrict__ csr,
                                              const float* __restrict__ dis,
                                              float* __restrict__ agg,
                                              float* __restrict__ statsA)
{
    __shared__ float sA[20];
    int t = threadIdx.x;
    if (t < 20) sA[t] = 0.f;
    __syncthreads();
    int n = blockIdx.x * 256 + t;
    float av[D_IN] = {0.f, 0.f, 0.f, 0.f, 0.f};
    if (n < N_NODES) {
        float sc[D_IN], sh[D_IN];
#pragma unroll
        for (int f = 0; f < D_IN; ++f) {
            float m = stats[f] * (1.0f / N_NODES);
            float var = stats[D_IN + f] * (1.0f / N_NODES) - m * m;
            sc[f] = rsqrtf(var + BN_EPS) * g0[f];
            sh[f] = be0[f] - m * sc[f];
        }
        float dn = dis[n];
        float acc[D_IN];
#pragma unroll
        for (int f = 0; f < D_IN; ++f)
            acc[f] = dn * (h[n * D_IN + f] * sc[f] + sh[f]);
        int e0 = rowptr[n], e1 = rowptr[n + 1];
        for (int e = e0; e < e1; ++e) {
            int2 pk = csr[e];
            int s = pk.x;
            float pn = __builtin_bit_cast(float, pk.y);
#pragma unroll
            for (int f = 0; f < D_IN; ++f)
                acc[f] += pn * (h[s * D_IN + f] * sc[f] + sh[f]);
        }
#pragma unroll
        for (int f = 0; f < D_IN; ++f) {
            float o = dn * acc[f];
            agg[n * D_IN + f] = o;
            av[f] = o;
        }
    }
    // 20-value reduction: Sa[0..4], then Saa upper triangle (k<=l)
    float red[20];
#pragma unroll
    for (int f = 0; f < D_IN; ++f) red[f] = av[f];
    {
        int idx = D_IN;
#pragma unroll
        for (int k = 0; k < D_IN; ++k)
#pragma unroll
            for (int l = k; l < D_IN; ++l)
                red[idx++] = av[k] * av[l];
    }
#pragma unroll
    for (int off = 32; off > 0; off >>= 1) {
#pragma unroll
        for (int i = 0; i < 20; ++i)
            red[i] += __shfl_down(red[i], off);
    }
    if ((t & 63) == 0) {
#pragma unroll
        for (int i = 0; i < 20; ++i)
            atomicAdd(&sA[i], red[i]);
    }
    __syncthreads();
    if (t < 20) atomicAdd(statsA + t, sA[t]);
}

// ---------------------------------------------------------------------------
// Layer-1 skinny GEMM (K=5) with fused CLOSED-FORM BN1 + ReLU applied in fp32
// before the bf16 round. MUST be launched with exactly 512 blocks x 256 thr.
// ---------------------------------------------------------------------------
__global__ __launch_bounds__(256) void k_l1(const float* __restrict__ agg,
                                            const float* __restrict__ W1,
                                            const float* __restrict__ b1,
                                            const float* __restrict__ g1,
                                            const float* __restrict__ be1,
                                            const float* __restrict__ statsA,
                                            unsigned short* __restrict__ x)
{
    int t = threadIdx.x;
    int idx0 = blockIdx.x * 256 + t;
    int f0 = (idx0 & 63) * 2;      // feature pair, constant per thread
    float wa[D_IN], wb[D_IN];
#pragma unroll
    for (int k = 0; k < D_IN; ++k) {
        wa[k] = W1[k * D_H + f0];
        wb[k] = W1[k * D_H + f0 + 1];
    }
    float ba = b1[f0], bb = b1[f0 + 1];

    // closed-form BN1 affine for this feature pair
    const float inv = 1.0f / N_NODES;
    float S1[D_IN];
#pragma unroll
    for (int k = 0; k < D_IN; ++k) S1[k] = statsA[k];
    float M[D_IN][D_IN];
    {
        int idx = D_IN;
#pragma unroll
        for (int k = 0; k < D_IN; ++k)
#pragma unroll
            for (int l = k; l < D_IN; ++l) {
                float v = statsA[idx++];
                M[k][l] = v;
                M[l][k] = v;
            }
    }
    float t1a = 0.f, t1b = 0.f, qa = 0.f, qb = 0.f;
#pragma unroll
    for (int k = 0; k < D_IN; ++k) { t1a += wa[k] * S1[k]; t1b += wb[k] * S1[k]; }
#pragma unroll
    for (int k = 0; k < D_IN; ++k) {
        float ra = 0.f, rb = 0.f;
#pragma unroll
        for (int l = 0; l < D_IN; ++l) { ra += M[k][l] * wa[l]; rb += M[k][l] * wb[l]; }
        qa += wa[k] * ra;
        qb += wb[k] * rb;
    }
    float ma = t1a * inv, mb = t1b * inv;           // mean of w.a (bias excluded)
    float mua = ma + ba, mub = mb + bb;
    float vara = fmaxf(qa * inv - ma * ma, 0.f);
    float varb = fmaxf(qb * inv - mb * mb, 0.f);
    float sca = rsqrtf(vara + BN_EPS) * g1[f0];
    float scb = rsqrtf(varb + BN_EPS) * g1[f0 + 1];
    float sha = be1[f0] - mua * sca;
    float shb = be1[f0 + 1] - mub * scb;

    const int stride = 512 * 256;
    for (int idx = idx0; idx < N_NODES * 64; idx += stride) {
        int n = idx >> 6;
        const float* a = agg + n * D_IN;
        float v0 = ba, v1 = bb;
#pragma unroll
        for (int k = 0; k < D_IN; ++k) { v0 += wa[k] * a[k]; v1 += wb[k] * a[k]; }
        v0 = fmaxf(v0 * sca + sha, 0.f);
        v1 = fmaxf(v1 * scb + shb, 0.f);
        ((unsigned*)x)[idx] = (unsigned)f2bfb(v0) | ((unsigned)f2bfb(v1) << 16);
    }
}

// ---------------------------------------------------------------------------
// 128-wide aggregation, x is already BN1+ReLU'd: pure weighted gather-sum.
// out[n] = dis[n]*(dis[n]*x[n] + sum pn*x[s]), bf16 out.
// One node per 16 lanes, 3125 blocks: max gather parallelism (proven R1).
// ---------------------------------------------------------------------------
__global__ __launch_bounds__(256) void k_agg128(const unsigned short* __restrict__ x,
                                                const int* __restrict__ rowptr,
                                                const int2* __restrict__ csr,
                                                const float* __restrict__ dis,
                                                unsigned short* __restrict__ outb)
{
    int t = threadIdx.x;
    int n = blockIdx.x * 16 + (t >> 4);
    int f0 = (t & 15) * 8;
    if (n >= N_NODES) return;
    float dn = dis[n];
    uint4 hv = *(const uint4*)(x + (size_t)n * D_H + f0);
    float a0 = dn * bflo(hv.x), a1 = dn * bfhi(hv.x);
    float a2 = dn * bflo(hv.y), a3 = dn * bfhi(hv.y);
    float a4 = dn * bflo(hv.z), a5 = dn * bfhi(hv.z);
    float a6 = dn * bflo(hv.w), a7 = dn * bfhi(hv.w);
    int e = rowptr[n], e1 = rowptr[n + 1];
    for (; e + 4 <= e1; e += 4) {
        int2 p0 = csr[e + 0], p1 = csr[e + 1], p2 = csr[e + 2], p3 = csr[e + 3];
        float w0 = __builtin_bit_cast(float, p0.y);
        float w1 = __builtin_bit_cast(float, p1.y);
        float w2 = __builtin_bit_cast(float, p2.y);
        float w3 = __builtin_bit_cast(float, p3.y);
        uint4 v0 = *(const uint4*)(x + (size_t)p0.x * D_H + f0);
        uint4 v1 = *(const uint4*)(x + (size_t)p1.x * D_H + f0);
        uint4 v2 = *(const uint4*)(x + (size_t)p2.x * D_H + f0);
        uint4 v3 = *(const uint4*)(x + (size_t)p3.x * D_H + f0);
        a0 += w0 * bflo(v0.x) + w1 * bflo(v1.x) + w2 * bflo(v2.x) + w3 * bflo(v3.x);
        a1 += w0 * bfhi(v0.x) + w1 * bfhi(v1.x) + w2 * bfhi(v2.x) + w3 * bfhi(v3.x);
        a2 += w0 * bflo(v0.y) + w1 * bflo(v1.y) + w2 * bflo(v2.y) + w3 * bflo(v3.y);
        a3 += w0 * bfhi(v0.y) + w1 * bfhi(v1.y) + w2 * bfhi(v2.y) + w3 * bfhi(v3.y);
        a4 += w0 * bflo(v0.z) + w1 * bflo(v1.z) + w2 * bflo(v2.z) + w3 * bflo(v3.z);
        a5 += w0 * bfhi(v0.z) + w1 * bfhi(v1.z) + w2 * bfhi(v2.z) + w3 * bfhi(v3.z);
        a6 += w0 * bflo(v0.w) + w1 * bflo(v1.w) + w2 * bflo(v2.w) + w3 * bflo(v3.w);
        a7 += w0 * bfhi(v0.w) + w1 * bfhi(v1.w) + w2 * bfhi(v2.w) + w3 * bfhi(v3.w);
    }
    for (; e < e1; ++e) {
        int2 pk = csr[e];
        float pn = __builtin_bit_cast(float, pk.y);
        uint4 v = *(const uint4*)(x + (size_t)pk.x * D_H + f0);
        a0 += pn * bflo(v.x); a1 += pn * bfhi(v.x);
        a2 += pn * bflo(v.y); a3 += pn * bfhi(v.y);
        a4 += pn * bflo(v.z); a5 += pn * bfhi(v.z);
        a6 += pn * bflo(v.w); a7 += pn * bfhi(v.w);
    }
    uint4 o;
    o.x = (unsigned)f2bfb(dn * a0) | ((unsigned)f2bfb(dn * a1) << 16);
    o.y = (unsigned)f2bfb(dn * a2) | ((unsigned)f2bfb(dn * a3) << 16);
    o.z = (unsigned)f2bfb(dn * a4) | ((unsigned)f2bfb(dn * a5) << 16);
    o.w = (unsigned)f2bfb(dn * a6) | ((unsigned)f2bfb(dn * a7) << 16);
    *(uint4*)(outb + (size_t)n * D_H + f0) = o;
}

// ---------------------------------------------------------------------------
// MFMA GEMM, LDS-staged B: C_bf16 = A_bf16 @ W + bias (pre-BN), fused stats.
// ---------------------------------------------------------------------------
__global__ __launch_bounds__(256) void k_gemm_mf(const unsigned short* __restrict__ A,
                                                 const unsigned short* __restrict__ Bt,
                                                 const float* __restrict__ bias,
                                                 unsigned short* __restrict__ C,
                                                 float* __restrict__ stats)
{
    __shared__ uint4 ldsB[2048];          // 32 KB fragment-major B
    __shared__ float sm_s[D_H], sm_q[D_H];
    int t = threadIdx.x;
    if (t < D_H) { sm_s[t] = 0.f; sm_q[t] = 0.f; }
    stage_b(Bt, ldsB, t);
    int wave = t >> 6, lane = t & 63;
    int m = lane & 15, quad = lane >> 4;
    int r0 = blockIdx.x * 64 + wave * 16;
    int arow = r0 + m < N_NODES ? r0 + m : N_NODES - 1;
    const bf16x8* ap = (const bf16x8*)(A + (size_t)arow * D_H + quad * 8);
    bf16x8 af[4];
#pragma unroll
    for (int ks = 0; ks < 4; ++ks) af[ks] = ap[ks * 4];
    __syncthreads();
    const bf16x8* bf = (const bf16x8*)ldsB;       // [fid*64 + lane]
    f32x4 acc[8];
#pragma unroll
    for (int ct = 0; ct < 8; ++ct) acc[ct] = (f32x4)(0.f);
#pragma unroll
    for (int ks = 0; ks < 4; ++ks) {
#pragma unroll
        for (int ct = 0; ct < 8; ++ct) {
            acc[ct] = __builtin_amdgcn_mfma_f32_16x16x32_bf16(
                af[ks], bf[(ct * 4 + ks) * 64 + lane], acc[ct], 0, 0, 0);
        }
    }
#pragma unroll
    for (int ct = 0; ct < 8; ++ct) {
        int col = ct * 16 + m;
        float bv = bias[col];
        float s = 0.f, q = 0.f;
#pragma unroll
        for (int r = 0; r < 4; ++r) {
            int rr = r0 + quad * 4 + r;
            if (rr < N_NODES) {
                float v = acc[ct][r] + bv;
                C[(size_t)rr * D_H + col] = f2bfb(v);
                s += v; q += v * v;
            }
        }
        atomicAdd(&sm_s[col], s);
        atomicAdd(&sm_q[col], q);
    }
    __syncthreads();
    if (t < D_H) {
        atomicAdd(stats + t, sm_s[t]);
        atomicAdd(stats + D_H + t, sm_q[t]);
    }
}

// ---------------------------------------------------------------------------
// MFMA dual GEMM with fused BN2+ReLU on the A fragments.
// mu -> out[0:N*128), log_std -> out[N*128:). fp32 out.
// ---------------------------------------------------------------------------
__global__ __launch_bounds__(256) void k_gemm_out_mf(const unsigned short* __restrict__ A,
                                                     const float* __restrict__ stats,
                                                     const float* __restrict__ g,
                                                     const float* __restrict__ be,
                                                     const unsigned short* __restrict__ Btmu,
                                                     const float* __restrict__ bmu,
                                                     const unsigned short* __restrict__ Btls,
                                                     const float* __restrict__ bls,
                                                     float* __restrict__ out)
{
    __shared__ uint4 ldsB[2048];          // 32 KB fragment-major B
    int t = threadIdx.x;
    int wave = t >> 6, lane = t & 63;
    int m = lane & 15, quad = lane >> 4;
    int r0 = blockIdx.x * 64 + wave * 16;
    int arow = r0 + m < N_NODES ? r0 + m : N_NODES - 1;
    const unsigned short* arowp = A + (size_t)arow * D_H + quad * 8;
    const float inv = 1.0f / N_NODES;
    bf16x8 af[4];
#pragma unroll
    for (int ks = 0; ks < 4; ++ks) {
        uint4 av = *(const uint4*)(arowp + ks * 32);
        float vals[8] = { bflo(av.x), bfhi(av.x), bflo(av.y), bfhi(av.y),
                          bflo(av.z), bfhi(av.z), bflo(av.w), bfhi(av.w) };
        int fb = quad * 8 + ks * 32;
        unsigned short o[8];
#pragma unroll
        for (int j = 0; j < 8; ++j) {
            int f = fb + j;
            float mm = stats[f] * inv;
            float var = stats[D_H + f] * inv - mm * mm;
            float scv = rsqrtf(var + BN_EPS) * g[f];
            float shv = be[f] - mm * scv;
            o[j] = f2bfb(fmaxf(vals[j] * scv + shv, 0.f));
        }
        uint4 pk;
        pk.x = (unsigned)o[0] | ((unsigned)o[1] << 16);
        pk.y = (unsigned)o[2] | ((unsigned)o[3] << 16);
        pk.z = (unsigned)o[4] | ((unsigned)o[5] << 16);
        pk.w = (unsigned)o[6] | ((unsigned)o[7] << 16);
        af[ks] = __builtin_bit_cast(bf16x8, pk);
    }
    const bf16x8* bf = (const bf16x8*)ldsB;
#pragma unroll
    for (int half = 0; half < 2; ++half) {
        if (half) __syncthreads();        // protect restage vs prior reads
        stage_b(half ? Btls : Btmu, ldsB, t);
        __syncthreads();
        const float* bias = half ? bls : bmu;
        float* C = out + (half ? (size_t)N_NODES * D_H : 0);
        f32x4 acc[8];
#pragma unroll
        for (int ct = 0; ct < 8; ++ct) acc[ct] = (f32x4)(0.f);
#pragma unroll
        for (int ks = 0; ks < 4; ++ks) {
#pragma unroll
            for (int ct = 0; ct < 8; ++ct) {
                acc[ct] = __builtin_amdgcn_mfma_f32_16x16x32_bf16(
                    af[ks], bf[(ct * 4 + ks) * 64 + lane], acc[ct], 0, 0, 0);
            }
        }
#pragma unroll
        for (int ct = 0; ct < 8; ++ct) {
            int col = ct * 16 + m;
            float bv = bias[col];
#pragma unroll
            for (int r = 0; r < 4; ++r) {
                int rr = r0 + quad * 4 + r;
                if (rr < N_NODES)
                    C[(size_t)rr * D_H + col] = acc[ct][r] + bv;
            }
        }
    }
}

// ---------------------------------------------------------------------------
extern "C" void kernel_launch(void* const* d_in, const int* in_sizes, int n_in,
                              void* d_out, int out_size, void* d_ws, size_t ws_size,
                              hipStream_t stream)
{
    const float* h   = (const float*)d_in[0];
    const int*   eidx = (const int*)d_in[1];
    const float* ew  = (const float*)d_in[2];
    const float* g0  = (const float*)d_in[3];
    const float* be0 = (const float*)d_in[4];
    const float* W1  = (const float*)d_in[5];
    const float* b1  = (const float*)d_in[6];
    const float* g1  = (const float*)d_in[7];
    const float* be1 = (const float*)d_in[8];
    const float* W2  = (const float*)d_in[9];
    const float* b2  = (const float*)d_in[10];
    const float* g2  = (const float*)d_in[11];
    const float* be2 = (const float*)d_in[12];
    const float* Wmu = (const float*)d_in[13];
    const float* bmu = (const float*)d_in[14];
    const float* Wls = (const float*)d_in[15];
    const float* bls = (const float*)d_in[16];
    const int* srcv = eidx;
    const int* dstv = eidx + N_EDGES;
    float* out = (float*)d_out;

    char* ws = (char*)d_ws;
    size_t off = 0;
    auto alloc = [&](size_t bytes) -> char* {
        char* p = ws + off;
        off += (bytes + 255) & ~(size_t)255;
        return p;
    };
    float* stats0  = (float*)alloc(16 * 4);
    float* statsA  = (float*)alloc(32 * 4);     // 20 used: Sa[5] + Saa[15]
    float* stats2  = (float*)alloc(256 * 4);
    unsigned long long* degcnt = (unsigned long long*)alloc(N_NODES * 8);
    size_t zero_bytes = off;                 // everything above must start at 0
    int*   rowptr  = (int*)  alloc((N_NODES + 1) * 4);
    float* dis     = (float*)alloc(N_NODES * 4);
    int*   rank    = (int*)  alloc((size_t)N_EDGES * 4);
    int*   blocksums = (int*)alloc(256 * 4);
    int2*  csr     = (int2*) alloc((size_t)N_EDGES * 8);
    float* agg0    = (float*)alloc(N_NODES * D_IN * 4);
    unsigned short* x1h  = (unsigned short*)alloc((size_t)N_NODES * D_H * 2);  // bf16 post-BN1+ReLU
    unsigned short* aggh = (unsigned short*)alloc((size_t)N_NODES * D_H * 2);  // bf16 agg
    unsigned short* c2h  = (unsigned short*)alloc((size_t)N_NODES * D_H * 2);  // bf16 pre-BN2
    unsigned short* Wt2   = (unsigned short*)alloc(D_H * D_H * 2);
    unsigned short* Wtmu  = (unsigned short*)alloc(D_H * D_H * 2);
    unsigned short* Wtls  = (unsigned short*)alloc(D_H * D_H * 2);
    (void)ws_size; (void)in_sizes; (void)n_in; (void)out_size;

    hipMemsetAsync(d_ws, 0, zero_bytes, stream);

    k_prep<<<192 + SCAN_BLOCKS + DEG_BLOCKS, 256, 0, stream>>>(
        W2, Wmu, Wls, Wt2, Wtmu, Wtls, h, stats0, dstv, ew, degcnt, rank);
    k_scan1<<<SCAN_BLOCKS, 256, 0, stream>>>(degcnt, dis, blocksums);
    k_scan3<<<SCAN_BLOCKS, 256, 0, stream>>>(degcnt, rowptr, blocksums);
    k_fill<<<DEG_BLOCKS, 256, 0, stream>>>(srcv, dstv, ew, dis, rowptr, rank, csr);
    k_agg0<<<SCAN_BLOCKS, 256, 0, stream>>>(h, stats0, g0, be0, rowptr, csr, dis,
                                            agg0, statsA);
    k_l1<<<512, 256, 0, stream>>>(agg0, W1, b1, g1, be1, statsA, x1h);
    k_agg128<<<(N_NODES + 15) / 16, 256, 0, stream>>>(x1h, rowptr, csr, dis, aggh);
    k_gemm_mf<<<(N_NODES + 63) / 64, 256, 0, stream>>>(aggh, Wt2, b2, c2h, stats2);
    k_gemm_out_mf<<<(N_NODES + 63) / 64, 256, 0, stream>>>(c2h, stats2, g2, be2,
                                                           Wtmu, bmu, Wtls, bls, out);
}